// Round 2
// baseline (292.986 us; speedup 1.0000x reference)
//
#include <hip/hip_runtime.h>
#include <hip/hip_bf16.h>

#define NEG_SLOPE 0.2f

// ---------------- CSR build (by dst), self-loops appended ----------------
__global__ void k_deg(const int* __restrict__ ei, int E, int N, int* __restrict__ deg){
  int i = blockIdx.x * blockDim.x + threadIdx.x;
  int Etot = E + N;
  if (i >= Etot) return;
  int d = (i < E) ? ei[E + i] : (i - E);
  atomicAdd(&deg[d], 1);
}

__global__ __launch_bounds__(1024) void k_scan(const int* __restrict__ deg, int* __restrict__ off, int n){
  __shared__ int lds[1024];
  int t = threadIdx.x;
  int per = (n + 1023) >> 10;
  int b = t * per, e = min(b + per, n);
  int sum = 0;
  for (int i = b; i < e; ++i) sum += deg[i];
  lds[t] = sum;
  __syncthreads();
  for (int d = 1; d < 1024; d <<= 1){
    int v = (t >= d) ? lds[t - d] : 0;
    __syncthreads();
    lds[t] += v;
    __syncthreads();
  }
  int run = (t == 0) ? 0 : lds[t - 1];
  for (int i = b; i < e; ++i){ off[i] = run; run += deg[i]; }
  if (t == 1023) off[n] = lds[1023];
}

__global__ void k_scatter(const int* __restrict__ ei, int E, int N,
                          const int* __restrict__ off, int* __restrict__ cur,
                          int* __restrict__ csr_src){
  int i = blockIdx.x * blockDim.x + threadIdx.x;
  int Etot = E + N;
  if (i >= Etot) return;
  int s, d;
  if (i < E){ s = ei[i]; d = ei[E + i]; } else { s = i - E; d = i - E; }
  int p = off[d] + atomicAdd(&cur[d], 1);
  csr_src[p] = s;
}

// ---------------- GEMM1: h1[N,512] = x[N,128] @ W1[128,512] (f32) ----------------
#define NPB 8
__global__ __launch_bounds__(256) void k_gemm1(const float* __restrict__ x,
                                               const float* __restrict__ W,
                                               float* __restrict__ h, int N){
  __shared__ float xs[NPB][128];
  int n0 = blockIdx.x * NPB;
  int t = threadIdx.x;
  for (int i = t; i < NPB * 128; i += 256){
    int nn = i >> 7, kk = i & 127;
    int n = n0 + nn;
    xs[nn][kk] = (n < N) ? x[(size_t)n * 128 + kk] : 0.0f;
  }
  __syncthreads();
  float acc[NPB][2];
  #pragma unroll
  for (int nn = 0; nn < NPB; ++nn){ acc[nn][0] = 0.f; acc[nn][1] = 0.f; }
  const float2* W2p = (const float2*)W;
  for (int k = 0; k < 128; ++k){
    float2 wv = W2p[k * 256 + t];
    #pragma unroll
    for (int nn = 0; nn < NPB; ++nn){
      float xv = xs[nn][k];
      acc[nn][0] += xv * wv.x;
      acc[nn][1] += xv * wv.y;
    }
  }
  for (int nn = 0; nn < NPB; ++nn){
    int n = n0 + nn;
    if (n >= N) break;
    float2 st = make_float2(acc[nn][0], acc[nn][1]);
    *(float2*)&h[(size_t)n * 512 + 2 * t] = st;
  }
}

// ---------------- attention scalars layer 1 ----------------
__global__ __launch_bounds__(256) void k_alpha1(const float* __restrict__ h,
                                                const float* __restrict__ aw_s,
                                                const float* __restrict__ aw_d,
                                                float* __restrict__ as, float* __restrict__ ad, int N){
  int n = blockIdx.x * 4 + (threadIdx.x >> 6);
  if (n >= N) return;
  int lane = threadIdx.x & 63;
  float s = 0.f, d = 0.f;
  for (int j = lane; j < 512; j += 64){
    float hv = h[(size_t)n * 512 + j];
    s += hv * aw_s[j];
    d += hv * aw_d[j];
  }
  for (int o = 32; o > 0; o >>= 1){ s += __shfl_down(s, o); d += __shfl_down(d, o); }
  if (lane == 0){ as[n] = s; ad[n] = d; }
}

// ---------------- per-dst softmax + aggregation (+bias +ReLU fused) ----------------
template<int F, int BLOCK>
__global__ __launch_bounds__(BLOCK) void k_agg(const int* __restrict__ off, const int* __restrict__ csr_src,
                      const float* __restrict__ as, const float* __restrict__ ad,
                      const float* __restrict__ h, const float* __restrict__ bias,
                      float* __restrict__ out, int N){
  int n = blockIdx.x;
  int t = threadIdx.x;
  int s0 = off[n], s1 = off[n + 1];
  int deg = s1 - s0;
  float adv = ad[n];
  // pass 1: online (max, sum) per thread, then block reduce
  float m = -__builtin_huge_valf(), ssum = 0.0f;
  for (int i = t; i < deg; i += BLOCK){
    int s = csr_src[s0 + i];
    float v = as[s] + adv;
    v = (v > 0.0f) ? v : NEG_SLOPE * v;
    if (v > m){ ssum = ssum * __expf(m - v) + 1.0f; m = v; }
    else ssum += __expf(v - m);
  }
  __shared__ float rm[BLOCK], rs[BLOCK];
  rm[t] = m; rs[t] = ssum;
  __syncthreads();
  for (int d = BLOCK / 2; d > 0; d >>= 1){
    if (t < d){
      float m2 = rm[t + d], sv2 = rs[t + d];
      float mm = fmaxf(rm[t], m2);
      float ns = 0.0f;
      if (rs[t] > 0.0f) ns += rs[t] * __expf(rm[t] - mm);
      if (sv2  > 0.0f) ns += sv2  * __expf(m2   - mm);
      rm[t] = mm; rs[t] = ns;
    }
    __syncthreads();
  }
  float gmax = rm[0];
  float invden = 1.0f / rs[0];
  constexpr int NACC = (F + BLOCK - 1) / BLOCK;
  float acc[NACC];
  #pragma unroll
  for (int r = 0; r < NACC; ++r) acc[r] = 0.0f;
  __shared__ float l_al[BLOCK];
  __shared__ int   l_sr[BLOCK];
  for (int base = 0; base < deg; base += BLOCK){
    int cnt = min(BLOCK, deg - base);
    __syncthreads();
    if (t < cnt){
      int s = csr_src[s0 + base + t];
      float v = as[s] + adv;
      v = (v > 0.0f) ? v : NEG_SLOPE * v;
      l_al[t] = __expf(v - gmax) * invden;
      l_sr[t] = s;
    }
    __syncthreads();
    for (int i = 0; i < cnt; ++i){
      float a = l_al[i];
      const float* hr = h + (size_t)l_sr[i] * F;
      #pragma unroll
      for (int r = 0; r < NACC; ++r){
        int f = t + r * BLOCK;
        acc[r] += a * hr[f];
      }
    }
  }
  #pragma unroll
  for (int r = 0; r < NACC; ++r){
    int f = t + r * BLOCK;
    float v = acc[r] + bias[f];
    out[(size_t)n * F + f] = fmaxf(v, 0.0f);
  }
}

// ---------------- GEMM2: h2[N,64] = g1[N,512] @ W2[512,64], fused alpha dots ----------------
__global__ __launch_bounds__(256) void k_gemm2(const float* __restrict__ g1,
                                               const float* __restrict__ W,
                                               const float* __restrict__ aw_s,
                                               const float* __restrict__ aw_d,
                                               float* __restrict__ h2,
                                               float* __restrict__ as, float* __restrict__ ad, int N){
  int n = blockIdx.x * 4 + (threadIdx.x >> 6);
  if (n >= N) return;
  int j = threadIdx.x & 63;
  const float4* g4 = (const float4*)(g1 + (size_t)n * 512);
  float acc = 0.0f;
  #pragma unroll 4
  for (int k4 = 0; k4 < 128; ++k4){
    float4 gv = g4[k4];
    int k = k4 * 4;
    acc += gv.x * W[(k + 0) * 64 + j];
    acc += gv.y * W[(k + 1) * 64 + j];
    acc += gv.z * W[(k + 2) * 64 + j];
    acc += gv.w * W[(k + 3) * 64 + j];
  }
  h2[(size_t)n * 64 + j] = acc;
  float s = acc * aw_s[j];
  float d = acc * aw_d[j];
  for (int o = 32; o > 0; o >>= 1){ s += __shfl_down(s, o); d += __shfl_down(d, o); }
  if (j == 0){ as[n] = s; ad[n] = d; }
}

// ---------------- global mean pool (atomic) ----------------
__global__ __launch_bounds__(256) void k_pool(const float* __restrict__ g2, const int* __restrict__ batch,
                                              float* __restrict__ pool, float* __restrict__ cnt, int N){
  int idx = blockIdx.x * blockDim.x + threadIdx.x;
  if (idx >= N * 64) return;
  int n = idx >> 6, f = idx & 63;
  int g = batch[n];
  atomicAdd(&pool[g * 64 + f], g2[idx]);
  if (f == 0) atomicAdd(&cnt[g], 1.0f);
}

// ---------------- final FC ----------------
__global__ __launch_bounds__(128) void k_fc(const float* __restrict__ pool, const float* __restrict__ cnt,
                                            const float* __restrict__ fcW,
                                            const float* __restrict__ fcb,
                                            float* __restrict__ out, int NG){
  int idx = threadIdx.x;
  if (idx >= NG * 2) return;
  int g = idx >> 1, o = idx & 1;
  float c = fmaxf(cnt[g], 1.0f);
  float s = 0.0f;
  for (int f = 0; f < 64; ++f) s += (pool[g * 64 + f] / c) * fcW[f * 2 + o];
  s += fcb[o];
  out[idx] = s;
}

extern "C" void kernel_launch(void* const* d_in, const int* in_sizes, int n_in,
                              void* d_out, int out_size, void* d_ws, size_t ws_size,
                              hipStream_t stream){
  const float* x    = (const float*)d_in[0];
  const int* ei     = (const int*)d_in[1];
  const int* batch  = (const int*)d_in[2];
  const float* W1   = (const float*)d_in[3];
  const float* as1w = (const float*)d_in[4];
  const float* ad1w = (const float*)d_in[5];
  const float* b1   = (const float*)d_in[6];
  const float* W2   = (const float*)d_in[7];
  const float* as2w = (const float*)d_in[8];
  const float* ad2w = (const float*)d_in[9];
  const float* b2   = (const float*)d_in[10];
  const float* fcW  = (const float*)d_in[11];
  const float* fcb  = (const float*)d_in[12];
  float* out = (float*)d_out;

  const int N    = in_sizes[2];
  const int E    = in_sizes[1] / 2;
  const int NG   = out_size / 2;
  const int Etot = E + N;

  char* base = (char*)d_ws;
  size_t o = 0;
  auto take = [&](size_t bytes) -> char* {
    char* r = base + o;
    o = (o + bytes + 255) & ~(size_t)255;
    return r;
  };
  float* h1   = (float*)take((size_t)N * 512 * 4);
  float* g1   = (float*)take((size_t)N * 512 * 4);
  float* h2   = (float*)take((size_t)N * 64 * 4);
  float* g2   = (float*)take((size_t)N * 64 * 4);
  float* as1  = (float*)take((size_t)N * 4);
  float* ad1  = (float*)take((size_t)N * 4);
  float* as2  = (float*)take((size_t)N * 4);
  float* ad2  = (float*)take((size_t)N * 4);
  int*   deg  = (int*)take((size_t)N * 4);
  int*   offs = (int*)take((size_t)(N + 1) * 4);
  int*   cur  = (int*)take((size_t)N * 4);
  int*   csr  = (int*)take((size_t)Etot * 4);
  float* pool = (float*)take((size_t)NG * 64 * 4);
  float* cnt  = (float*)take((size_t)NG * 4);

  hipMemsetAsync(deg, 0, (size_t)N * 4, stream);
  hipMemsetAsync(cur, 0, (size_t)N * 4, stream);
  hipMemsetAsync(pool, 0, (size_t)NG * 64 * 4, stream);
  hipMemsetAsync(cnt, 0, (size_t)NG * 4, stream);

  k_deg<<<(Etot + 255) / 256, 256, 0, stream>>>(ei, E, N, deg);
  k_scan<<<1, 1024, 0, stream>>>(deg, offs, N);
  k_scatter<<<(Etot + 255) / 256, 256, 0, stream>>>(ei, E, N, offs, cur, csr);

  k_gemm1<<<(N + NPB - 1) / NPB, 256, 0, stream>>>(x, W1, h1, N);
  k_alpha1<<<(N + 3) / 4, 256, 0, stream>>>(h1, as1w, ad1w, as1, ad1, N);
  k_agg<512, 256><<<N, 256, 0, stream>>>(offs, csr, as1, ad1, h1, b1, g1, N);

  k_gemm2<<<(N + 3) / 4, 256, 0, stream>>>(g1, W2, as2w, ad2w, h2, as2, ad2, N);
  k_agg<64, 64><<<N, 64, 0, stream>>>(offs, csr, as2, ad2, h2, b2, g2, N);

  k_pool<<<((size_t)N * 64 + 255) / 256, 256, 0, stream>>>(g2, batch, pool, cnt, N);
  k_fc<<<1, 128, 0, stream>>>(pool, cnt, fcW, fcb, out, NG);
}

// Round 3
// 244.568 us; speedup vs baseline: 1.1980x; 1.1980x over previous
//
#include <hip/hip_runtime.h>
#include <hip/hip_bf16.h>

#define NEG_SLOPE 0.2f

// ---------------- CSR build (by dst), self-loops appended ----------------
__global__ void k_deg(const int* __restrict__ ei, int E, int N, int* __restrict__ deg){
  int i = blockIdx.x * blockDim.x + threadIdx.x;
  int Etot = E + N;
  if (i >= Etot) return;
  int d = (i < E) ? ei[E + i] : (i - E);
  atomicAdd(&deg[d], 1);
}

__global__ __launch_bounds__(1024) void k_scan(const int* __restrict__ deg, int* __restrict__ off, int n){
  __shared__ int lds[1024];
  int t = threadIdx.x;
  int per = (n + 1023) >> 10;
  int b = t * per, e = min(b + per, n);
  int sum = 0;
  for (int i = b; i < e; ++i) sum += deg[i];
  lds[t] = sum;
  __syncthreads();
  for (int d = 1; d < 1024; d <<= 1){
    int v = (t >= d) ? lds[t - d] : 0;
    __syncthreads();
    lds[t] += v;
    __syncthreads();
  }
  int run = (t == 0) ? 0 : lds[t - 1];
  for (int i = b; i < e; ++i){ off[i] = run; run += deg[i]; }
  if (t == 1023) off[n] = lds[1023];
}

__global__ void k_scatter(const int* __restrict__ ei, int E, int N,
                          const int* __restrict__ off, int* __restrict__ cur,
                          int* __restrict__ csr_src){
  int i = blockIdx.x * blockDim.x + threadIdx.x;
  int Etot = E + N;
  if (i >= Etot) return;
  int s, d;
  if (i < E){ s = ei[i]; d = ei[E + i]; } else { s = i - E; d = i - E; }
  int p = off[d] + atomicAdd(&cur[d], 1);
  csr_src[p] = s;
}

// ---------------- projected attention vectors: ws = W @ a_src, wd = W @ a_dst ----------------
__global__ __launch_bounds__(64) void k_wvec(const float* __restrict__ W1, const float* __restrict__ as1,
                                             const float* __restrict__ ad1,
                                             const float* __restrict__ W2, const float* __restrict__ as2,
                                             const float* __restrict__ ad2,
                                             float* __restrict__ ws1, float* __restrict__ wd1,
                                             float* __restrict__ ws2, float* __restrict__ wd2){
  int b = blockIdx.x, l = threadIdx.x;
  float s = 0.f, d = 0.f;
  if (b < 128){
    #pragma unroll
    for (int j = l; j < 512; j += 64){ float w = W1[b * 512 + j]; s += w * as1[j]; d += w * ad1[j]; }
  } else {
    int r = b - 128;
    float w = W2[r * 64 + l];
    s = w * as2[l]; d = w * ad2[l];
  }
  #pragma unroll
  for (int o = 32; o > 0; o >>= 1){ s += __shfl_xor(s, o); d += __shfl_xor(d, o); }
  if (l == 0){
    if (b < 128){ ws1[b] = s; wd1[b] = d; }
    else        { ws2[b - 128] = s; wd2[b - 128] = d; }
  }
}

// ---------------- attention logit scalars, layer 1 (from x, 128-dim) ----------------
__global__ __launch_bounds__(256) void k_alphax(const float* __restrict__ x, const float* __restrict__ ws,
                                                const float* __restrict__ wd,
                                                float* __restrict__ as, float* __restrict__ ad, int N){
  int n = blockIdx.x * 4 + (threadIdx.x >> 6);
  if (n >= N) return;
  int l = threadIdx.x & 63;
  float x0 = x[(size_t)n * 128 + l], x1 = x[(size_t)n * 128 + 64 + l];
  float s = x0 * ws[l] + x1 * ws[64 + l];
  float d = x0 * wd[l] + x1 * wd[64 + l];
  #pragma unroll
  for (int o = 32; o > 0; o >>= 1){ s += __shfl_xor(s, o); d += __shfl_xor(d, o); }
  if (l == 0){ as[n] = s; ad[n] = d; }
}

// ---------------- attention logit scalars, layer 2 (from g1, 512-dim) ----------------
__global__ __launch_bounds__(256) void k_alpha2(const float* __restrict__ g1, const float* __restrict__ ws,
                                                const float* __restrict__ wd,
                                                float* __restrict__ as, float* __restrict__ ad, int N){
  int n = blockIdx.x * 4 + (threadIdx.x >> 6);
  if (n >= N) return;
  int l = threadIdx.x & 63;
  const float4* g4 = (const float4*)(g1 + (size_t)n * 512);
  const float4* w4s = (const float4*)ws;
  const float4* w4d = (const float4*)wd;
  float4 a0 = g4[l], a1 = g4[64 + l];
  float4 s0 = w4s[l], s1 = w4s[64 + l];
  float4 d0 = w4d[l], d1 = w4d[64 + l];
  float s = a0.x*s0.x + a0.y*s0.y + a0.z*s0.z + a0.w*s0.w
          + a1.x*s1.x + a1.y*s1.y + a1.z*s1.z + a1.w*s1.w;
  float d = a0.x*d0.x + a0.y*d0.y + a0.z*d0.z + a0.w*d0.w
          + a1.x*d1.x + a1.y*d1.y + a1.z*d1.z + a1.w*d1.w;
  #pragma unroll
  for (int o = 32; o > 0; o >>= 1){ s += __shfl_xor(s, o); d += __shfl_xor(d, o); }
  if (l == 0){ as[n] = s; ad[n] = d; }
}

// ---------------- wave-per-node softmax aggregation ----------------
template<int F, bool EPI>
__global__ __launch_bounds__(256) void k_aggw(const int* __restrict__ off, const int* __restrict__ csr,
    const float* __restrict__ as, const float* __restrict__ ad, const float* __restrict__ h,
    const float* __restrict__ bias, float* __restrict__ out, int N){
  int n = blockIdx.x * 4 + (threadIdx.x >> 6);
  if (n >= N) return;
  int l = threadIdx.x & 63;
  int s0 = off[n];
  int deg = off[n + 1] - s0;
  float adv = ad[n];
  float m = -3.0e38f, ssum = 0.f;
  int cs = 0; float cv = -3.0e38f;
  for (int i = l; i < deg; i += 64){
    int s = csr[s0 + i];
    float v = as[s] + adv;
    v = (v > 0.f) ? v : NEG_SLOPE * v;
    if (i < 64){ cs = s; cv = v; }
    if (v > m){ ssum = ssum * __expf(m - v) + 1.f; m = v; }
    else ssum += __expf(v - m);
  }
  #pragma unroll
  for (int o = 32; o > 0; o >>= 1){
    float m2 = __shfl_xor(m, o);
    float s2 = __shfl_xor(ssum, o);
    float mm = fmaxf(m, m2);
    float ns = 0.f;
    if (ssum > 0.f) ns += ssum * __expf(m - mm);
    if (s2  > 0.f) ns += s2  * __expf(m2 - mm);
    m = mm; ssum = ns;
  }
  float inv = 1.0f / ssum;
  constexpr int NACC = F / 64;
  float acc[NACC];
  #pragma unroll
  for (int r = 0; r < NACC; ++r) acc[r] = 0.f;
  for (int base = 0; base < deg; base += 64){
    int cnt = min(64, deg - base);
    float al; int sr;
    if (base == 0){
      sr = cs;
      al = (l < deg) ? __expf(cv - m) * inv : 0.f;
    } else {
      int idx = base + l;
      if (idx < deg){
        sr = csr[s0 + idx];
        float v = as[sr] + adv;
        v = (v > 0.f) ? v : NEG_SLOPE * v;
        al = __expf(v - m) * inv;
      } else { sr = 0; al = 0.f; }
    }
    for (int i = 0; i < cnt; ++i){
      float a = __shfl(al, i);
      int s  = __shfl(sr, i);
      const float* hr = h + (size_t)s * F;
      #pragma unroll
      for (int r = 0; r < NACC; ++r) acc[r] += a * hr[l + r * 64];
    }
  }
  #pragma unroll
  for (int r = 0; r < NACC; ++r){
    float v = acc[r];
    if (EPI){ v += bias[l + r * 64]; v = fmaxf(v, 0.f); }
    out[(size_t)n * F + l + r * 64] = v;
  }
}

// ---------------- GEMM1: g1[N,512] = ReLU(xa[N,128] @ W1 + b1) ----------------
// one wave per 8 rows; row operand via wave-uniform float4 loads; 64 indep accumulators/lane
__global__ __launch_bounds__(128) void k_gemm1(const float* __restrict__ xa, const float* __restrict__ W,
                                               const float* __restrict__ bias, float* __restrict__ g1, int N){
  int l = threadIdx.x & 63;
  int n0 = (blockIdx.x * 2 + (threadIdx.x >> 6)) * 8;
  float acc[8][8];
  #pragma unroll
  for (int a = 0; a < 8; ++a)
    #pragma unroll
    for (int c = 0; c < 8; ++c) acc[a][c] = 0.f;
  const float4* xa4 = (const float4*)xa;
  for (int k4 = 0; k4 < 32; ++k4){
    float4 g[8];
    #pragma unroll
    for (int nn = 0; nn < 8; ++nn){
      int n = n0 + nn; n = (n < N) ? n : (N - 1);
      g[nn] = xa4[(size_t)n * 32 + k4];
    }
    #pragma unroll
    for (int kk = 0; kk < 4; ++kk){
      float w[8];
      #pragma unroll
      for (int c = 0; c < 8; ++c) w[c] = W[(size_t)(k4 * 4 + kk) * 512 + c * 64 + l];
      #pragma unroll
      for (int nn = 0; nn < 8; ++nn){
        float gv = (kk == 0) ? g[nn].x : (kk == 1) ? g[nn].y : (kk == 2) ? g[nn].z : g[nn].w;
        #pragma unroll
        for (int c = 0; c < 8; ++c) acc[nn][c] += gv * w[c];
      }
    }
  }
  #pragma unroll
  for (int nn = 0; nn < 8; ++nn){
    int n = n0 + nn;
    if (n >= N) break;
    #pragma unroll
    for (int c = 0; c < 8; ++c){
      float v = acc[nn][c] + bias[c * 64 + l];
      g1[(size_t)n * 512 + c * 64 + l] = fmaxf(v, 0.f);
    }
  }
}

// ---------------- GEMM2: h2[N,64] = g1[N,512] @ W2 ----------------
__global__ __launch_bounds__(64) void k_gemm2(const float* __restrict__ g1, const float* __restrict__ W,
                                              float* __restrict__ h2, int N){
  int j = threadIdx.x;
  int n0 = blockIdx.x * 8;
  float acc[8];
  #pragma unroll
  for (int a = 0; a < 8; ++a) acc[a] = 0.f;
  const float4* g4 = (const float4*)g1;
  for (int k4 = 0; k4 < 128; ++k4){
    float4 g[8];
    #pragma unroll
    for (int nn = 0; nn < 8; ++nn){
      int n = n0 + nn; n = (n < N) ? n : (N - 1);
      g[nn] = g4[(size_t)n * 128 + k4];
    }
    #pragma unroll
    for (int kk = 0; kk < 4; ++kk){
      float w = W[(size_t)(k4 * 4 + kk) * 64 + j];
      #pragma unroll
      for (int nn = 0; nn < 8; ++nn){
        float gv = (kk == 0) ? g[nn].x : (kk == 1) ? g[nn].y : (kk == 2) ? g[nn].z : g[nn].w;
        acc[nn] += gv * w;
      }
    }
  }
  #pragma unroll
  for (int nn = 0; nn < 8; ++nn){
    int n = n0 + nn;
    if (n < N) h2[(size_t)n * 64 + j] = acc[nn];
  }
}

// ---------------- mean pool via sorted-batch segments ----------------
__device__ __forceinline__ int lbound(const int* a, int n, int v){
  int lo = 0, hi = n;
  while (lo < hi){ int mid = (lo + hi) >> 1; if (a[mid] < v) lo = mid + 1; else hi = mid; }
  return lo;
}

__global__ __launch_bounds__(256) void k_pool(const float* __restrict__ g2, const int* __restrict__ batch,
                                              float* __restrict__ pool, int N){
  int g = blockIdx.x;
  __shared__ int sb[2];
  if (threadIdx.x == 0){ sb[0] = lbound(batch, N, g); sb[1] = lbound(batch, N, g + 1); }
  __syncthreads();
  int r0 = sb[0], r1 = sb[1];
  int f = threadIdx.x & 63, ch = threadIdx.x >> 6;
  float s = 0.f;
  for (int r = r0 + ch; r < r1; r += 4) s += g2[(size_t)r * 64 + f];
  __shared__ float red[4][64];
  red[ch][f] = s;
  __syncthreads();
  if (ch == 0){
    float tot = red[0][f] + red[1][f] + red[2][f] + red[3][f];
    float c = fmaxf((float)(r1 - r0), 1.f);
    pool[g * 64 + f] = tot / c;
  }
}

__global__ __launch_bounds__(128) void k_fc(const float* __restrict__ pool,
                                            const float* __restrict__ fcW, const float* __restrict__ fcb,
                                            float* __restrict__ out, int NG){
  int idx = threadIdx.x;
  if (idx >= NG * 2) return;
  int g = idx >> 1, o = idx & 1;
  float s = 0.f;
  for (int f = 0; f < 64; ++f) s += pool[g * 64 + f] * fcW[f * 2 + o];
  out[idx] = s + fcb[o];
}

extern "C" void kernel_launch(void* const* d_in, const int* in_sizes, int n_in,
                              void* d_out, int out_size, void* d_ws, size_t ws_size,
                              hipStream_t stream){
  const float* x    = (const float*)d_in[0];
  const int* ei     = (const int*)d_in[1];
  const int* batch  = (const int*)d_in[2];
  const float* W1   = (const float*)d_in[3];
  const float* as1w = (const float*)d_in[4];
  const float* ad1w = (const float*)d_in[5];
  const float* b1   = (const float*)d_in[6];
  const float* W2   = (const float*)d_in[7];
  const float* as2w = (const float*)d_in[8];
  const float* ad2w = (const float*)d_in[9];
  const float* b2   = (const float*)d_in[10];
  const float* fcW  = (const float*)d_in[11];
  const float* fcb  = (const float*)d_in[12];
  float* out = (float*)d_out;

  const int N    = in_sizes[2];
  const int E    = in_sizes[1] / 2;
  const int NG   = out_size / 2;
  const int Etot = E + N;

  char* base = (char*)d_ws;
  size_t o = 0;
  auto take = [&](size_t bytes) -> char* {
    char* r = base + o;
    o = (o + bytes + 255) & ~(size_t)255;
    return r;
  };
  float* xa   = (float*)take((size_t)(N + 8) * 128 * 4);
  float* g1   = (float*)take((size_t)(N + 8) * 512 * 4);
  float* h2   = (float*)take((size_t)(N + 8) * 64 * 4);
  float* g2   = (float*)take((size_t)(N + 8) * 64 * 4);
  float* as1  = (float*)take((size_t)N * 4);
  float* ad1  = (float*)take((size_t)N * 4);
  float* as2  = (float*)take((size_t)N * 4);
  float* ad2  = (float*)take((size_t)N * 4);
  float* ws1  = (float*)take(128 * 4);
  float* wd1  = (float*)take(128 * 4);
  float* ws2  = (float*)take(512 * 4);
  float* wd2  = (float*)take(512 * 4);
  int*   deg  = (int*)take((size_t)N * 4);
  int*   offs = (int*)take((size_t)(N + 1) * 4);
  int*   cur  = (int*)take((size_t)N * 4);
  int*   csr  = (int*)take((size_t)Etot * 4);
  float* pool = (float*)take((size_t)NG * 64 * 4);

  hipMemsetAsync(deg, 0, (size_t)N * 4, stream);
  hipMemsetAsync(cur, 0, (size_t)N * 4, stream);

  k_deg<<<(Etot + 255) / 256, 256, 0, stream>>>(ei, E, N, deg);
  k_scan<<<1, 1024, 0, stream>>>(deg, offs, N);
  k_scatter<<<(Etot + 255) / 256, 256, 0, stream>>>(ei, E, N, offs, cur, csr);

  k_wvec<<<640, 64, 0, stream>>>(W1, as1w, ad1w, W2, as2w, ad2w, ws1, wd1, ws2, wd2);
  k_alphax<<<(N + 3) / 4, 256, 0, stream>>>(x, ws1, wd1, as1, ad1, N);
  k_aggw<128, false><<<(N + 3) / 4, 256, 0, stream>>>(offs, csr, as1, ad1, x, b1, xa, N);
  k_gemm1<<<(N + 15) / 16, 128, 0, stream>>>(xa, W1, b1, g1, N);

  k_alpha2<<<(N + 3) / 4, 256, 0, stream>>>(g1, ws2, wd2, as2, ad2, N);
  k_gemm2<<<(N + 7) / 8, 64, 0, stream>>>(g1, W2, h2, N);
  k_aggw<64, true><<<(N + 3) / 4, 256, 0, stream>>>(offs, csr, as2, ad2, h2, b2, g2, N);

  k_pool<<<NG, 256, 0, stream>>>(g2, batch, pool, N);
  k_fc<<<1, 128, 0, stream>>>(pool, fcW, fcb, out, NG);
}

// Round 4
// 163.347 us; speedup vs baseline: 1.7936x; 1.4972x over previous
//
#include <hip/hip_runtime.h>
#include <hip/hip_bf16.h>

#define NEG_SLOPE 0.2f

// ---------------- CSR build (by dst), self-loops appended ----------------
__global__ void k_deg(const int* __restrict__ ei, int E, int N, int* __restrict__ deg){
  int i = blockIdx.x * blockDim.x + threadIdx.x;
  int Etot = E + N;
  if (i >= Etot) return;
  int d = (i < E) ? ei[E + i] : (i - E);
  atomicAdd(&deg[d], 1);
}

__global__ __launch_bounds__(1024) void k_scan(const int* __restrict__ deg, int* __restrict__ off, int n){
  __shared__ int lds[1024];
  int t = threadIdx.x;
  int per = (n + 1023) >> 10;
  int b = t * per, e = min(b + per, n);
  int sum = 0;
  for (int i = b; i < e; ++i) sum += deg[i];
  lds[t] = sum;
  __syncthreads();
  for (int d = 1; d < 1024; d <<= 1){
    int v = (t >= d) ? lds[t - d] : 0;
    __syncthreads();
    lds[t] += v;
    __syncthreads();
  }
  int run = (t == 0) ? 0 : lds[t - 1];
  for (int i = b; i < e; ++i){ off[i] = run; run += deg[i]; }
  if (t == 1023) off[n] = lds[1023];
}

__global__ void k_scatter(const int* __restrict__ ei, int E, int N,
                          const int* __restrict__ off, int* __restrict__ cur,
                          int* __restrict__ csr_src){
  int i = blockIdx.x * blockDim.x + threadIdx.x;
  int Etot = E + N;
  if (i >= Etot) return;
  int s, d;
  if (i < E){ s = ei[i]; d = ei[E + i]; } else { s = i - E; d = i - E; }
  int p = off[d] + atomicAdd(&cur[d], 1);
  csr_src[p] = s;
}

// ---------------- projected attention vectors: ws = W @ a_src, wd = W @ a_dst ----------------
__global__ __launch_bounds__(64) void k_wvec(const float* __restrict__ W1, const float* __restrict__ as1,
                                             const float* __restrict__ ad1,
                                             const float* __restrict__ W2, const float* __restrict__ as2,
                                             const float* __restrict__ ad2,
                                             float* __restrict__ ws1, float* __restrict__ wd1,
                                             float* __restrict__ ws2, float* __restrict__ wd2){
  int b = blockIdx.x, l = threadIdx.x;
  float s = 0.f, d = 0.f;
  if (b < 128){
    #pragma unroll
    for (int j = l; j < 512; j += 64){ float w = W1[b * 512 + j]; s += w * as1[j]; d += w * ad1[j]; }
  } else {
    int r = b - 128;
    float w = W2[r * 64 + l];
    s = w * as2[l]; d = w * ad2[l];
  }
  #pragma unroll
  for (int o = 32; o > 0; o >>= 1){ s += __shfl_xor(s, o); d += __shfl_xor(d, o); }
  if (l == 0){
    if (b < 128){ ws1[b] = s; wd1[b] = d; }
    else        { ws2[b - 128] = s; wd2[b - 128] = d; }
  }
}

// ---------------- attention logit scalars, layer 1 (from x, 128-dim) ----------------
__global__ __launch_bounds__(256) void k_alphax(const float* __restrict__ x, const float* __restrict__ ws,
                                                const float* __restrict__ wd,
                                                float* __restrict__ as, float* __restrict__ ad, int N){
  int n = blockIdx.x * 4 + (threadIdx.x >> 6);
  if (n >= N) return;
  int l = threadIdx.x & 63;
  float x0 = x[(size_t)n * 128 + l], x1 = x[(size_t)n * 128 + 64 + l];
  float s = x0 * ws[l] + x1 * ws[64 + l];
  float d = x0 * wd[l] + x1 * wd[64 + l];
  #pragma unroll
  for (int o = 32; o > 0; o >>= 1){ s += __shfl_xor(s, o); d += __shfl_xor(d, o); }
  if (l == 0){ as[n] = s; ad[n] = d; }
}

// ---------------- wave-per-node softmax aggregation ----------------
// F=128: float2 per lane (gathers x rows -> xa).  F=64: float per lane (gathers h2 -> g2, +bias+relu).
template<int F, bool EPI>
__global__ __launch_bounds__(256) void k_aggw(const int* __restrict__ off, const int* __restrict__ csr,
    const float* __restrict__ as, const float* __restrict__ ad, const float* __restrict__ h,
    const float* __restrict__ bias, float* __restrict__ out, int N){
  int n = blockIdx.x * 4 + (threadIdx.x >> 6);
  if (n >= N) return;
  int l = threadIdx.x & 63;
  int s0 = off[n];
  int deg = off[n + 1] - s0;
  float adv = ad[n];
  float m = -3.0e38f, ssum = 0.f;
  for (int i = l; i < deg; i += 64){
    int s = csr[s0 + i];
    float v = as[s] + adv;
    v = (v > 0.f) ? v : NEG_SLOPE * v;
    if (v > m){ ssum = ssum * __expf(m - v) + 1.f; m = v; }
    else ssum += __expf(v - m);
  }
  #pragma unroll
  for (int o = 32; o > 0; o >>= 1){
    float m2 = __shfl_xor(m, o);
    float s2 = __shfl_xor(ssum, o);
    float mm = fmaxf(m, m2);
    float ns = 0.f;
    if (ssum > 0.f) ns += ssum * __expf(m - mm);
    if (s2  > 0.f) ns += s2  * __expf(m2 - mm);
    m = mm; ssum = ns;
  }
  float inv = 1.0f / ssum;

  float2 acc = make_float2(0.f, 0.f);
  for (int base = 0; base < deg; base += 64){
    int idx = base + l;
    float al = 0.f; int sr = 0;
    if (idx < deg){
      sr = csr[s0 + idx];
      float v = as[sr] + adv;
      v = (v > 0.f) ? v : NEG_SLOPE * v;
      al = __expf(v - m) * inv;
    }
    int cnt = min(64, deg - base);
    #pragma unroll 4
    for (int i = 0; i < cnt; ++i){
      float a = __shfl(al, i);
      int s  = __shfl(sr, i);
      if (F == 128){
        float2 hv = ((const float2*)(h + (size_t)s * 128))[l];
        acc.x += a * hv.x; acc.y += a * hv.y;
      } else {
        acc.x += a * h[(size_t)s * 64 + l];
      }
    }
  }
  if (F == 128){
    ((float2*)(out + (size_t)n * 128))[l] = acc;
  } else {
    float v = acc.x;
    if (EPI){ v += bias[l]; v = fmaxf(v, 0.f); }
    out[(size_t)n * 64 + l] = v;
  }
}

// ---------------- fused layer kernel ----------------
// per block (256 thr, 16 rows): g1 = ReLU(xa@W1 + b1) in regs -> as2/ad2 (wave-reduce)
//                               -> g1 tile to LDS -> h2 = g1@W2
#define LROWS 16
#define GPAD 516
__global__ __launch_bounds__(256) void k_layer(
    const float* __restrict__ xa, const float* __restrict__ W1, const float* __restrict__ b1,
    const float* __restrict__ W2, const float* __restrict__ ws2, const float* __restrict__ wd2,
    float* __restrict__ h2, float* __restrict__ as2, float* __restrict__ ad2, int N){
  __shared__ float gs[LROWS][GPAD];            // 33 KB; first 8 KB doubles as x-tile
  float (*xs)[128] = (float(*)[128])gs;
  int t = threadIdx.x;
  int n0 = blockIdx.x * LROWS;
  const float4* xa4 = (const float4*)xa;
  for (int i = t; i < LROWS * 32; i += 256){
    int nn = i >> 5, k4 = i & 31;
    int n = n0 + nn; if (n >= N) n = N - 1;
    ((float4*)(xs[nn]))[k4] = xa4[(size_t)n * 32 + k4];
  }
  __syncthreads();
  int w = t >> 6, j = t & 63;
  int r0 = w * 4;
  float acc[4][8];
  #pragma unroll
  for (int r = 0; r < 4; ++r)
    #pragma unroll
    for (int c = 0; c < 8; ++c) acc[r][c] = 0.f;

  #pragma unroll 2
  for (int k = 0; k < 128; ++k){
    float xv[4];
    #pragma unroll
    for (int r = 0; r < 4; ++r) xv[r] = xs[r0 + r][k];
    float wv[8];
    #pragma unroll
    for (int c = 0; c < 8; ++c) wv[c] = W1[(size_t)k * 512 + c * 64 + j];
    #pragma unroll
    for (int r = 0; r < 4; ++r)
      #pragma unroll
      for (int c = 0; c < 8; ++c) acc[r][c] += xv[r] * wv[c];
  }

  float bv[8], wsv[8], wdv[8];
  #pragma unroll
  for (int c = 0; c < 8; ++c){
    bv[c]  = b1[c * 64 + j];
    wsv[c] = ws2[c * 64 + j];
    wdv[c] = wd2[c * 64 + j];
  }
  __syncthreads();   // done reading x-tile; gs stores may now overwrite it

  float ps[4] = {0,0,0,0}, pd[4] = {0,0,0,0};
  #pragma unroll
  for (int r = 0; r < 4; ++r){
    #pragma unroll
    for (int c = 0; c < 8; ++c){
      float g = fmaxf(acc[r][c] + bv[c], 0.f);
      gs[r0 + r][c * 64 + j] = g;
      ps[r] += g * wsv[c];
      pd[r] += g * wdv[c];
    }
  }
  #pragma unroll
  for (int o = 32; o > 0; o >>= 1){
    #pragma unroll
    for (int r = 0; r < 4; ++r){ ps[r] += __shfl_xor(ps[r], o); pd[r] += __shfl_xor(pd[r], o); }
  }
  if (j == 0){
    #pragma unroll
    for (int r = 0; r < 4; ++r){
      int n = n0 + r0 + r;
      if (n < N){ as2[n] = ps[r]; ad2[n] = pd[r]; }
    }
  }
  __syncthreads();

  float acc2[4] = {0,0,0,0};
  #pragma unroll 2
  for (int k4 = 0; k4 < 128; ++k4){
    float4 gr[4];
    #pragma unroll
    for (int r = 0; r < 4; ++r) gr[r] = *(const float4*)&gs[r0 + r][k4 * 4];
    float wv2[4];
    #pragma unroll
    for (int kk = 0; kk < 4; ++kk) wv2[kk] = W2[(size_t)(k4 * 4 + kk) * 64 + j];
    #pragma unroll
    for (int r = 0; r < 4; ++r)
      acc2[r] += gr[r].x * wv2[0] + gr[r].y * wv2[1] + gr[r].z * wv2[2] + gr[r].w * wv2[3];
  }
  #pragma unroll
  for (int r = 0; r < 4; ++r){
    int n = n0 + r0 + r;
    if (n < N) h2[(size_t)n * 64 + j] = acc2[r];
  }
}

// ---------------- mean pool via sorted-batch segments ----------------
__device__ __forceinline__ int lbound(const int* a, int n, int v){
  int lo = 0, hi = n;
  while (lo < hi){ int mid = (lo + hi) >> 1; if (a[mid] < v) lo = mid + 1; else hi = mid; }
  return lo;
}

__global__ __launch_bounds__(256) void k_pool(const float* __restrict__ g2, const int* __restrict__ batch,
                                              float* __restrict__ pool, int N){
  int g = blockIdx.x;
  __shared__ int sb[2];
  if (threadIdx.x == 0){ sb[0] = lbound(batch, N, g); sb[1] = lbound(batch, N, g + 1); }
  __syncthreads();
  int r0 = sb[0], r1 = sb[1];
  int f = threadIdx.x & 63, ch = threadIdx.x >> 6;
  float s = 0.f;
  for (int r = r0 + ch; r < r1; r += 4) s += g2[(size_t)r * 64 + f];
  __shared__ float red[4][64];
  red[ch][f] = s;
  __syncthreads();
  if (ch == 0){
    float tot = red[0][f] + red[1][f] + red[2][f] + red[3][f];
    float c = fmaxf((float)(r1 - r0), 1.f);
    pool[g * 64 + f] = tot / c;
  }
}

__global__ __launch_bounds__(128) void k_fc(const float* __restrict__ pool,
                                            const float* __restrict__ fcW, const float* __restrict__ fcb,
                                            float* __restrict__ out, int NG){
  int idx = threadIdx.x;
  if (idx >= NG * 2) return;
  int g = idx >> 1, o = idx & 1;
  float s = 0.f;
  for (int f = 0; f < 64; ++f) s += pool[g * 64 + f] * fcW[f * 2 + o];
  out[idx] = s + fcb[o];
}

extern "C" void kernel_launch(void* const* d_in, const int* in_sizes, int n_in,
                              void* d_out, int out_size, void* d_ws, size_t ws_size,
                              hipStream_t stream){
  const float* x    = (const float*)d_in[0];
  const int* ei     = (const int*)d_in[1];
  const int* batch  = (const int*)d_in[2];
  const float* W1   = (const float*)d_in[3];
  const float* as1w = (const float*)d_in[4];
  const float* ad1w = (const float*)d_in[5];
  const float* b1   = (const float*)d_in[6];
  const float* W2   = (const float*)d_in[7];
  const float* as2w = (const float*)d_in[8];
  const float* ad2w = (const float*)d_in[9];
  const float* b2   = (const float*)d_in[10];
  const float* fcW  = (const float*)d_in[11];
  const float* fcb  = (const float*)d_in[12];
  float* out = (float*)d_out;

  const int N    = in_sizes[2];
  const int E    = in_sizes[1] / 2;
  const int NG   = out_size / 2;
  const int Etot = E + N;

  char* base = (char*)d_ws;
  size_t o = 0;
  auto take = [&](size_t bytes) -> char* {
    char* r = base + o;
    o = (o + bytes + 255) & ~(size_t)255;
    return r;
  };
  float* xa   = (float*)take((size_t)(N + 16) * 128 * 4);
  float* h2   = (float*)take((size_t)(N + 16) * 64 * 4);
  float* g2   = (float*)take((size_t)(N + 16) * 64 * 4);
  float* as1  = (float*)take((size_t)N * 4);
  float* ad1  = (float*)take((size_t)N * 4);
  float* as2  = (float*)take((size_t)N * 4);
  float* ad2  = (float*)take((size_t)N * 4);
  float* ws1  = (float*)take(128 * 4);
  float* wd1  = (float*)take(128 * 4);
  float* ws2  = (float*)take(512 * 4);
  float* wd2  = (float*)take(512 * 4);
  int*   deg  = (int*)take((size_t)N * 4);
  int*   offs = (int*)take((size_t)(N + 1) * 4);
  int*   cur  = (int*)take((size_t)N * 4);
  int*   csr  = (int*)take((size_t)Etot * 4);
  float* pool = (float*)take((size_t)NG * 64 * 4);

  hipMemsetAsync(deg, 0, (size_t)N * 4, stream);
  hipMemsetAsync(cur, 0, (size_t)N * 4, stream);

  k_deg<<<(Etot + 255) / 256, 256, 0, stream>>>(ei, E, N, deg);
  k_scan<<<1, 1024, 0, stream>>>(deg, offs, N);
  k_scatter<<<(Etot + 255) / 256, 256, 0, stream>>>(ei, E, N, offs, cur, csr);

  k_wvec<<<640, 64, 0, stream>>>(W1, as1w, ad1w, W2, as2w, ad2w, ws1, wd1, ws2, wd2);
  k_alphax<<<(N + 3) / 4, 256, 0, stream>>>(x, ws1, wd1, as1, ad1, N);
  k_aggw<128, false><<<(N + 3) / 4, 256, 0, stream>>>(offs, csr, as1, ad1, x, b1, xa, N);

  k_layer<<<(N + LROWS - 1) / LROWS, 256, 0, stream>>>(xa, W1, b1, W2, ws2, wd2, h2, as2, ad2, N);

  k_aggw<64, true><<<(N + 3) / 4, 256, 0, stream>>>(offs, csr, as2, ad2, h2, b2, g2, N);

  k_pool<<<NG, 256, 0, stream>>>(g2, batch, pool, N);
  k_fc<<<1, 128, 0, stream>>>(pool, fcW, fcb, out, NG);
}

// Round 5
// 155.421 us; speedup vs baseline: 1.8851x; 1.0510x over previous
//
#include <hip/hip_runtime.h>
#include <hip/hip_bf16.h>

#define NEG_SLOPE 0.2f

// ---------------- kA: degree histogram + projected attention vectors ----------------
// blocks [0, nDeg): histogram of dst into deg[]
// blocks [nDeg, nDeg+160): ws1/wd1 (128 outputs, 512-dot) and ws2/wd2 (512 outputs, 64-dot)
__global__ __launch_bounds__(256) void kA(const int* __restrict__ ei, int E, int N,
                                          int* __restrict__ deg,
                                          const float* __restrict__ W1, const float* __restrict__ as1,
                                          const float* __restrict__ ad1,
                                          const float* __restrict__ W2, const float* __restrict__ as2,
                                          const float* __restrict__ ad2,
                                          float* __restrict__ ws1, float* __restrict__ wd1,
                                          float* __restrict__ ws2, float* __restrict__ wd2,
                                          int nDeg){
  int blk = blockIdx.x;
  if (blk < nDeg){
    int i = blk * 256 + threadIdx.x;
    int Etot = E + N;
    if (i >= Etot) return;
    int d = (i < E) ? ei[E + i] : (i - E);
    atomicAdd(&deg[d], 1);
    return;
  }
  int b = (blk - nDeg) * 4 + (threadIdx.x >> 6);
  int l = threadIdx.x & 63;
  float s = 0.f, d = 0.f;
  if (b < 128){
    #pragma unroll
    for (int j = l; j < 512; j += 64){ float w = W1[b * 512 + j]; s += w * as1[j]; d += w * ad1[j]; }
  } else {
    int r = b - 128;                 // r in [0,512)
    float w = W2[r * 64 + l];
    s = w * as2[l]; d = w * ad2[l];
  }
  #pragma unroll
  for (int o = 32; o > 0; o >>= 1){ s += __shfl_xor(s, o); d += __shfl_xor(d, o); }
  if (l == 0){
    if (b < 128){ ws1[b] = s; wd1[b] = d; }
    else        { ws2[b - 128] = s; wd2[b - 128] = d; }
  }
}

__global__ __launch_bounds__(1024) void k_scan(const int* __restrict__ deg, int* __restrict__ off, int n){
  __shared__ int lds[1024];
  int t = threadIdx.x;
  int per = (n + 1023) >> 10;
  int b = t * per, e = min(b + per, n);
  int sum = 0;
  for (int i = b; i < e; ++i) sum += deg[i];
  lds[t] = sum;
  __syncthreads();
  for (int d = 1; d < 1024; d <<= 1){
    int v = (t >= d) ? lds[t - d] : 0;
    __syncthreads();
    lds[t] += v;
    __syncthreads();
  }
  int run = (t == 0) ? 0 : lds[t - 1];
  for (int i = b; i < e; ++i){ off[i] = run; run += deg[i]; }
  if (t == 1023) off[n] = lds[1023];
}

// ---------------- kC: CSR scatter + layer-1 logit scalars ----------------
__global__ __launch_bounds__(256) void kC(const int* __restrict__ ei, int E, int N,
                                          const int* __restrict__ off, int* __restrict__ cur,
                                          int* __restrict__ csr,
                                          const float* __restrict__ x, const float* __restrict__ ws,
                                          const float* __restrict__ wd,
                                          float* __restrict__ as, float* __restrict__ ad,
                                          int nScat){
  int blk = blockIdx.x;
  if (blk < nScat){
    int i = blk * 256 + threadIdx.x;
    int Etot = E + N;
    if (i >= Etot) return;
    int s, d;
    if (i < E){ s = ei[i]; d = ei[E + i]; } else { s = i - E; d = i - E; }
    int p = off[d] + atomicAdd(&cur[d], 1);
    csr[p] = s;
    return;
  }
  int n = (blk - nScat) * 4 + (threadIdx.x >> 6);
  if (n >= N) return;
  int l = threadIdx.x & 63;
  float2 xv = ((const float2*)(x + (size_t)n * 128))[l];
  float2 sv = ((const float2*)ws)[l];
  float2 dv = ((const float2*)wd)[l];
  float s = xv.x * sv.x + xv.y * sv.y;
  float d = xv.x * dv.x + xv.y * dv.y;
  #pragma unroll
  for (int o = 32; o > 0; o >>= 1){ s += __shfl_xor(s, o); d += __shfl_xor(d, o); }
  if (l == 0){ as[n] = s; ad[n] = d; }
}

// ---------------- wave-per-node softmax aggregation, edge-slot x float4 layout ----------------
// F=128: 2 edge slots x 32 feature lanes (float4).  F=64: 4 edge slots x 16 feature lanes.
template<int F, bool EPI>
__global__ __launch_bounds__(256) void k_aggw(const int* __restrict__ off, const int* __restrict__ csr,
    const float* __restrict__ as, const float* __restrict__ ad, const float* __restrict__ h,
    const float* __restrict__ bias, float* __restrict__ out, int N){
  int n = blockIdx.x * 4 + (threadIdx.x >> 6);
  if (n >= N) return;
  int l = threadIdx.x & 63;
  int s0 = off[n];
  int deg = off[n + 1] - s0;
  float adv = ad[n];
  float m = -3.0e38f, ssum = 0.f;
  for (int i = l; i < deg; i += 64){
    int s = csr[s0 + i];
    float v = as[s] + adv;
    v = (v > 0.f) ? v : NEG_SLOPE * v;
    if (v > m){ ssum = ssum * __expf(m - v) + 1.f; m = v; }
    else ssum += __expf(v - m);
  }
  #pragma unroll
  for (int o = 32; o > 0; o >>= 1){
    float m2 = __shfl_xor(m, o);
    float s2 = __shfl_xor(ssum, o);
    float mm = fmaxf(m, m2);
    float ns = 0.f;
    if (ssum > 0.f) ns += ssum * __expf(m - mm);
    if (s2  > 0.f) ns += s2  * __expf(m2 - mm);
    m = mm; ssum = ns;
  }
  float inv = 1.0f / ssum;

  constexpr int EPG = (F == 128) ? 2 : 4;   // edge slots per step
  constexpr int FL  = (F == 128) ? 32 : 16; // float4 lanes per edge
  int p = l / FL;
  int f = l % FL;
  float4 acc = make_float4(0.f, 0.f, 0.f, 0.f);
  for (int base = 0; base < deg; base += 64){
    int idx = base + l;
    float al = 0.f; int sr = 0;
    if (idx < deg){
      sr = csr[s0 + idx];
      float v = as[sr] + adv;
      v = (v > 0.f) ? v : NEG_SLOPE * v;
      al = __expf(v - m) * inv;
    }
    int cnt = min(64, deg - base);
    int steps = (cnt + EPG - 1) / EPG;
    #pragma unroll 4
    for (int i = 0; i < steps; ++i){
      int e = i * EPG + p;
      float a = __shfl(al, e);
      int s  = __shfl(sr, e);
      float4 hv = ((const float4*)(h + (size_t)s * F))[f];
      acc.x += a * hv.x; acc.y += a * hv.y; acc.z += a * hv.z; acc.w += a * hv.w;
    }
  }
  if (F == 64){
    acc.x += __shfl_xor(acc.x, 16); acc.y += __shfl_xor(acc.y, 16);
    acc.z += __shfl_xor(acc.z, 16); acc.w += __shfl_xor(acc.w, 16);
  }
  acc.x += __shfl_xor(acc.x, 32); acc.y += __shfl_xor(acc.y, 32);
  acc.z += __shfl_xor(acc.z, 32); acc.w += __shfl_xor(acc.w, 32);
  if (l < FL){
    if (EPI){
      float4 bv = ((const float4*)bias)[f];
      acc.x = fmaxf(acc.x + bv.x, 0.f); acc.y = fmaxf(acc.y + bv.y, 0.f);
      acc.z = fmaxf(acc.z + bv.z, 0.f); acc.w = fmaxf(acc.w + bv.w, 0.f);
    }
    ((float4*)(out + (size_t)n * F))[f] = acc;
  }
}

// ---------------- fused layer kernel: 8 rows/block, 256 thr, 2 rows/wave ----------------
#define LROWS 8
#define GPAD 516
__global__ __launch_bounds__(256) void k_layer(
    const float* __restrict__ xa, const float* __restrict__ W1, const float* __restrict__ b1,
    const float* __restrict__ W2, const float* __restrict__ ws2, const float* __restrict__ wd2,
    float* __restrict__ h2, float* __restrict__ as2, float* __restrict__ ad2, int N){
  __shared__ float gs[LROWS][GPAD];            // 16.5 KB; first 4 KB doubles as x-tile
  float (*xs)[128] = (float(*)[128])gs;
  int t = threadIdx.x;
  int n0 = blockIdx.x * LROWS;
  {
    int nn = t >> 5, k4 = t & 31;
    int n = n0 + nn; if (n >= N) n = N - 1;
    ((float4*)(xs[nn]))[k4] = ((const float4*)xa)[(size_t)n * 32 + k4];
  }
  __syncthreads();
  int w = t >> 6, j = t & 63;
  int r0 = w * 2;
  float acc[2][8];
  #pragma unroll
  for (int r = 0; r < 2; ++r)
    #pragma unroll
    for (int c = 0; c < 8; ++c) acc[r][c] = 0.f;

  #pragma unroll 2
  for (int k = 0; k < 128; ++k){
    float xv0 = xs[r0][k], xv1 = xs[r0 + 1][k];
    float wv[8];
    #pragma unroll
    for (int c = 0; c < 8; ++c) wv[c] = W1[(size_t)k * 512 + c * 64 + j];
    #pragma unroll
    for (int c = 0; c < 8; ++c){ acc[0][c] += xv0 * wv[c]; acc[1][c] += xv1 * wv[c]; }
  }

  float bv[8], wsv[8], wdv[8];
  #pragma unroll
  for (int c = 0; c < 8; ++c){
    bv[c]  = b1[c * 64 + j];
    wsv[c] = ws2[c * 64 + j];
    wdv[c] = wd2[c * 64 + j];
  }
  __syncthreads();   // done reading x-tile

  float ps[2] = {0, 0}, pd[2] = {0, 0};
  #pragma unroll
  for (int r = 0; r < 2; ++r){
    #pragma unroll
    for (int c = 0; c < 8; ++c){
      float g = fmaxf(acc[r][c] + bv[c], 0.f);
      gs[r0 + r][c * 64 + j] = g;
      ps[r] += g * wsv[c];
      pd[r] += g * wdv[c];
    }
  }
  #pragma unroll
  for (int o = 32; o > 0; o >>= 1){
    #pragma unroll
    for (int r = 0; r < 2; ++r){ ps[r] += __shfl_xor(ps[r], o); pd[r] += __shfl_xor(pd[r], o); }
  }
  if (j == 0){
    #pragma unroll
    for (int r = 0; r < 2; ++r){
      int n = n0 + r0 + r;
      if (n < N){ as2[n] = ps[r]; ad2[n] = pd[r]; }
    }
  }
  __syncthreads();

  float acc2[2] = {0, 0};
  #pragma unroll 2
  for (int k4 = 0; k4 < 128; ++k4){
    float4 g0 = *(const float4*)&gs[r0][k4 * 4];
    float4 g1 = *(const float4*)&gs[r0 + 1][k4 * 4];
    float w0 = W2[(size_t)(k4 * 4 + 0) * 64 + j];
    float w1 = W2[(size_t)(k4 * 4 + 1) * 64 + j];
    float w2 = W2[(size_t)(k4 * 4 + 2) * 64 + j];
    float w3 = W2[(size_t)(k4 * 4 + 3) * 64 + j];
    acc2[0] += g0.x * w0 + g0.y * w1 + g0.z * w2 + g0.w * w3;
    acc2[1] += g1.x * w0 + g1.y * w1 + g1.z * w2 + g1.w * w3;
  }
  #pragma unroll
  for (int r = 0; r < 2; ++r){
    int n = n0 + r0 + r;
    if (n < N) h2[(size_t)n * 64 + j] = acc2[r];
  }
}

// ---------------- mean pool + FC fused: one block per graph ----------------
__device__ __forceinline__ int lbound(const int* a, int n, int v){
  int lo = 0, hi = n;
  while (lo < hi){ int mid = (lo + hi) >> 1; if (a[mid] < v) lo = mid + 1; else hi = mid; }
  return lo;
}

__global__ __launch_bounds__(256) void k_poolfc(const float* __restrict__ g2, const int* __restrict__ batch,
                                                const float* __restrict__ fcW, const float* __restrict__ fcb,
                                                float* __restrict__ out, int N){
  int g = blockIdx.x;
  __shared__ int sb[2];
  if (threadIdx.x == 0){ sb[0] = lbound(batch, N, g); sb[1] = lbound(batch, N, g + 1); }
  __syncthreads();
  int r0 = sb[0], r1 = sb[1];
  int f = threadIdx.x & 63, ch = threadIdx.x >> 6;
  float s = 0.f;
  for (int r = r0 + ch; r < r1; r += 4) s += g2[(size_t)r * 64 + f];
  __shared__ float red[4][64];
  red[ch][f] = s;
  __syncthreads();
  if (ch == 0){
    float tot = red[0][f] + red[1][f] + red[2][f] + red[3][f];
    float c = fmaxf((float)(r1 - r0), 1.f);
    float p = tot / c;
    float o0 = p * fcW[f * 2 + 0];
    float o1 = p * fcW[f * 2 + 1];
    #pragma unroll
    for (int o = 32; o > 0; o >>= 1){ o0 += __shfl_xor(o0, o); o1 += __shfl_xor(o1, o); }
    if (f == 0){ out[g * 2 + 0] = o0 + fcb[0]; out[g * 2 + 1] = o1 + fcb[1]; }
  }
}

extern "C" void kernel_launch(void* const* d_in, const int* in_sizes, int n_in,
                              void* d_out, int out_size, void* d_ws, size_t ws_size,
                              hipStream_t stream){
  const float* x    = (const float*)d_in[0];
  const int* ei     = (const int*)d_in[1];
  const int* batch  = (const int*)d_in[2];
  const float* W1   = (const float*)d_in[3];
  const float* as1w = (const float*)d_in[4];
  const float* ad1w = (const float*)d_in[5];
  const float* b1   = (const float*)d_in[6];
  const float* W2   = (const float*)d_in[7];
  const float* as2w = (const float*)d_in[8];
  const float* ad2w = (const float*)d_in[9];
  const float* b2   = (const float*)d_in[10];
  const float* fcW  = (const float*)d_in[11];
  const float* fcb  = (const float*)d_in[12];
  float* out = (float*)d_out;

  const int N    = in_sizes[2];
  const int E    = in_sizes[1] / 2;
  const int NG   = out_size / 2;
  const int Etot = E + N;

  char* base = (char*)d_ws;
  size_t o = 0;
  auto take = [&](size_t bytes) -> char* {
    char* r = base + o;
    o = (o + bytes + 255) & ~(size_t)255;
    return r;
  };
  float* xa   = (float*)take((size_t)(N + 16) * 128 * 4);
  float* h2   = (float*)take((size_t)(N + 16) * 64 * 4);
  float* g2   = (float*)take((size_t)(N + 16) * 64 * 4);
  float* as1  = (float*)take((size_t)N * 4);
  float* ad1  = (float*)take((size_t)N * 4);
  float* as2  = (float*)take((size_t)N * 4);
  float* ad2  = (float*)take((size_t)N * 4);
  float* ws1  = (float*)take(128 * 4);
  float* wd1  = (float*)take(128 * 4);
  float* ws2  = (float*)take(512 * 4);
  float* wd2  = (float*)take(512 * 4);
  int*   deg  = (int*)take((size_t)N * 4);
  int*   offs = (int*)take((size_t)(N + 1) * 4);
  int*   cur  = (int*)take((size_t)N * 4);
  int*   csr  = (int*)take((size_t)Etot * 4);

  hipMemsetAsync(deg, 0, (size_t)N * 4, stream);
  hipMemsetAsync(cur, 0, (size_t)N * 4, stream);

  const int nDeg  = (Etot + 255) / 256;
  const int nWvec = 160;                       // 640 outputs / 4 per block
  kA<<<nDeg + nWvec, 256, 0, stream>>>(ei, E, N, deg, W1, as1w, ad1w, W2, as2w, ad2w,
                                       ws1, wd1, ws2, wd2, nDeg);
  k_scan<<<1, 1024, 0, stream>>>(deg, offs, N);
  const int nScat = nDeg;
  kC<<<nScat + (N + 3) / 4, 256, 0, stream>>>(ei, E, N, offs, cur, csr, x, ws1, wd1, as1, ad1, nScat);

  k_aggw<128, false><<<(N + 3) / 4, 256, 0, stream>>>(offs, csr, as1, ad1, x, b1, xa, N);
  k_layer<<<(N + LROWS - 1) / LROWS, 256, 0, stream>>>(xa, W1, b1, W2, ws2, wd2, h2, as2, ad2, N);
  k_aggw<64, true><<<(N + 3) / 4, 256, 0, stream>>>(offs, csr, as2, ad2, h2, b2, g2, N);

  k_poolfc<<<NG, 256, 0, stream>>>(g2, batch, fcW, fcb, out, N);
}

// Round 6
// 139.268 us; speedup vs baseline: 2.1038x; 1.1160x over previous
//
#include <hip/hip_runtime.h>
#include <hip/hip_bf16.h>

#define NEG_SLOPE 0.2f

// ---------------- kA: degree histogram + projected attention vectors ----------------
__global__ __launch_bounds__(256) void kA(const int* __restrict__ ei, int E, int N,
                                          int* __restrict__ deg,
                                          const float* __restrict__ W1, const float* __restrict__ as1,
                                          const float* __restrict__ ad1,
                                          const float* __restrict__ W2, const float* __restrict__ as2,
                                          const float* __restrict__ ad2,
                                          float* __restrict__ ws1, float* __restrict__ wd1,
                                          float* __restrict__ ws2, float* __restrict__ wd2,
                                          int nDeg){
  int blk = blockIdx.x;
  if (blk < nDeg){
    int i = blk * 256 + threadIdx.x;
    int Etot = E + N;
    if (i >= Etot) return;
    int d = (i < E) ? ei[E + i] : (i - E);
    atomicAdd(&deg[d], 1);
    return;
  }
  int b = (blk - nDeg) * 4 + (threadIdx.x >> 6);
  int l = threadIdx.x & 63;
  float s = 0.f, d = 0.f;
  if (b < 128){
    #pragma unroll
    for (int j = l; j < 512; j += 64){ float w = W1[b * 512 + j]; s += w * as1[j]; d += w * ad1[j]; }
  } else {
    int r = b - 128;
    float w = W2[r * 64 + l];
    s = w * as2[l]; d = w * ad2[l];
  }
  #pragma unroll
  for (int o = 32; o > 0; o >>= 1){ s += __shfl_xor(s, o); d += __shfl_xor(d, o); }
  if (l == 0){
    if (b < 128){ ws1[b] = s; wd1[b] = d; }
    else        { ws2[b - 128] = s; wd2[b - 128] = d; }
  }
}

__global__ __launch_bounds__(1024) void k_scan(const int* __restrict__ deg, int* __restrict__ off, int n){
  __shared__ int lds[1024];
  int t = threadIdx.x;
  int per = (n + 1023) >> 10;
  int b = t * per, e = min(b + per, n);
  int sum = 0;
  for (int i = b; i < e; ++i) sum += deg[i];
  lds[t] = sum;
  __syncthreads();
  for (int d = 1; d < 1024; d <<= 1){
    int v = (t >= d) ? lds[t - d] : 0;
    __syncthreads();
    lds[t] += v;
    __syncthreads();
  }
  int run = (t == 0) ? 0 : lds[t - 1];
  for (int i = b; i < e; ++i){ off[i] = run; run += deg[i]; }
  if (t == 1023) off[n] = lds[1023];
}

// ---------------- kC: CSR scatter + layer-1 logit scalars ----------------
__global__ __launch_bounds__(256) void kC(const int* __restrict__ ei, int E, int N,
                                          const int* __restrict__ off, int* __restrict__ cur,
                                          int* __restrict__ csr,
                                          const float* __restrict__ x, const float* __restrict__ ws,
                                          const float* __restrict__ wd,
                                          float* __restrict__ as, float* __restrict__ ad,
                                          int nScat){
  int blk = blockIdx.x;
  if (blk < nScat){
    int i = blk * 256 + threadIdx.x;
    int Etot = E + N;
    if (i >= Etot) return;
    int s, d;
    if (i < E){ s = ei[i]; d = ei[E + i]; } else { s = i - E; d = i - E; }
    int p = off[d] + atomicAdd(&cur[d], 1);
    csr[p] = s;
    return;
  }
  int n = (blk - nScat) * 4 + (threadIdx.x >> 6);
  if (n >= N) return;
  int l = threadIdx.x & 63;
  float2 xv = ((const float2*)(x + (size_t)n * 128))[l];
  float2 sv = ((const float2*)ws)[l];
  float2 dv = ((const float2*)wd)[l];
  float s = xv.x * sv.x + xv.y * sv.y;
  float d = xv.x * dv.x + xv.y * dv.y;
  #pragma unroll
  for (int o = 32; o > 0; o >>= 1){ s += __shfl_xor(s, o); d += __shfl_xor(d, o); }
  if (l == 0){ as[n] = s; ad[n] = d; }
}

// ---------------- wave-per-node softmax aggregation, edge-slot x float4 layout ----------------
template<int F, bool EPI>
__global__ __launch_bounds__(256) void k_aggw(const int* __restrict__ off, const int* __restrict__ csr,
    const float* __restrict__ as, const float* __restrict__ ad, const float* __restrict__ h,
    const float* __restrict__ bias, float* __restrict__ out, int N){
  int n = blockIdx.x * 4 + (threadIdx.x >> 6);
  if (n >= N) return;
  int l = threadIdx.x & 63;
  int s0 = off[n];
  int deg = off[n + 1] - s0;
  float adv = ad[n];
  float m = -3.0e38f, ssum = 0.f;
  for (int i = l; i < deg; i += 64){
    int s = csr[s0 + i];
    float v = as[s] + adv;
    v = (v > 0.f) ? v : NEG_SLOPE * v;
    if (v > m){ ssum = ssum * __expf(m - v) + 1.f; m = v; }
    else ssum += __expf(v - m);
  }
  #pragma unroll
  for (int o = 32; o > 0; o >>= 1){
    float m2 = __shfl_xor(m, o);
    float s2 = __shfl_xor(ssum, o);
    float mm = fmaxf(m, m2);
    float ns = 0.f;
    if (ssum > 0.f) ns += ssum * __expf(m - mm);
    if (s2  > 0.f) ns += s2  * __expf(m2 - mm);
    m = mm; ssum = ns;
  }
  float inv = 1.0f / ssum;

  constexpr int EPG = (F == 128) ? 2 : 4;
  constexpr int FL  = (F == 128) ? 32 : 16;
  int p = l / FL;
  int f = l % FL;
  float4 acc = make_float4(0.f, 0.f, 0.f, 0.f);
  for (int base = 0; base < deg; base += 64){
    int idx = base + l;
    float al = 0.f; int sr = 0;
    if (idx < deg){
      sr = csr[s0 + idx];
      float v = as[sr] + adv;
      v = (v > 0.f) ? v : NEG_SLOPE * v;
      al = __expf(v - m) * inv;
    }
    int cnt = min(64, deg - base);
    int steps = (cnt + EPG - 1) / EPG;
    #pragma unroll 4
    for (int i = 0; i < steps; ++i){
      int e = i * EPG + p;
      float a = __shfl(al, e);
      int s  = __shfl(sr, e);
      float4 hv = ((const float4*)(h + (size_t)s * F))[f];
      acc.x += a * hv.x; acc.y += a * hv.y; acc.z += a * hv.z; acc.w += a * hv.w;
    }
  }
  if (F == 64){
    acc.x += __shfl_xor(acc.x, 16); acc.y += __shfl_xor(acc.y, 16);
    acc.z += __shfl_xor(acc.z, 16); acc.w += __shfl_xor(acc.w, 16);
  }
  acc.x += __shfl_xor(acc.x, 32); acc.y += __shfl_xor(acc.y, 32);
  acc.z += __shfl_xor(acc.z, 32); acc.w += __shfl_xor(acc.w, 32);
  if (l < FL){
    if (EPI){
      float4 bv = ((const float4*)bias)[f];
      acc.x = fmaxf(acc.x + bv.x, 0.f); acc.y = fmaxf(acc.y + bv.y, 0.f);
      acc.z = fmaxf(acc.z + bv.z, 0.f); acc.w = fmaxf(acc.w + bv.w, 0.f);
    }
    ((float4*)(out + (size_t)n * F))[f] = acc;
  }
}

// ---------------- fused layer kernel v3 ----------------
// 256 thr, 16 rows/block.
// Phase A: wave w computes cols [w*128,(w+1)*128) for all 16 rows  -> W1 read ONCE per block.
// Phase B: wave w computes k in [w*128,(w+1)*128) for all rows/cols -> W2 read ONCE per block.
#define LROWS 16
#define GPAD 516
__global__ __launch_bounds__(256) void k_layer(
    const float* __restrict__ xa, const float* __restrict__ W1, const float* __restrict__ b1,
    const float* __restrict__ W2, const float* __restrict__ ws2, const float* __restrict__ wd2,
    float* __restrict__ h2, float* __restrict__ as2, float* __restrict__ ad2, int N){
  __shared__ float gs[LROWS][GPAD];        // 33 KB; first 8 KB doubles as x-tile
  __shared__ float red2[4][LROWS][64];     // 16 KB
  __shared__ float sred[4][LROWS][2];      // 0.5 KB
  float (*xs)[128] = (float(*)[128])gs;
  int t = threadIdx.x;
  int w = t >> 6, j = t & 63;
  int n0 = blockIdx.x * LROWS;

  {
    const float4* xa4 = (const float4*)xa;
    #pragma unroll
    for (int i = 0; i < 2; ++i){
      int idx = t + i * 256;             // 512 float4 = 16 rows x 32
      int nn = idx >> 5, k4 = idx & 31;
      int n = n0 + nn; if (n >= N) n = N - 1;
      ((float4*)(xs[nn]))[k4] = xa4[(size_t)n * 32 + k4];
    }
  }
  __syncthreads();

  // ---- phase A ----
  int c0 = w * 128;
  float acc0[LROWS], acc1[LROWS];
  #pragma unroll
  for (int r = 0; r < LROWS; ++r){ acc0[r] = 0.f; acc1[r] = 0.f; }
  for (int k4 = 0; k4 < 32; ++k4){
    float wa[4], wb[4];
    #pragma unroll
    for (int kk = 0; kk < 4; ++kk){
      const float* wr = W1 + (size_t)(k4 * 4 + kk) * 512 + c0;
      wa[kk] = wr[j]; wb[kk] = wr[64 + j];
    }
    #pragma unroll
    for (int r = 0; r < LROWS; ++r){
      float4 xv = *(const float4*)&xs[r][k4 * 4];
      acc0[r] += xv.x * wa[0] + xv.y * wa[1] + xv.z * wa[2] + xv.w * wa[3];
      acc1[r] += xv.x * wb[0] + xv.y * wb[1] + xv.z * wb[2] + xv.w * wb[3];
    }
  }

  float bv0 = b1[c0 + j],  bv1 = b1[c0 + 64 + j];
  float ws0 = ws2[c0 + j], ws1v = ws2[c0 + 64 + j];
  float wd0 = wd2[c0 + j], wd1v = wd2[c0 + 64 + j];
  __syncthreads();   // done reading x-tile

  float ps[LROWS], pd[LROWS];
  #pragma unroll
  for (int r = 0; r < LROWS; ++r){
    float g0 = fmaxf(acc0[r] + bv0, 0.f);
    float g1 = fmaxf(acc1[r] + bv1, 0.f);
    gs[r][c0 + j] = g0;
    gs[r][c0 + 64 + j] = g1;
    ps[r] = g0 * ws0 + g1 * ws1v;
    pd[r] = g0 * wd0 + g1 * wd1v;
  }
  #pragma unroll
  for (int o = 32; o > 0; o >>= 1){
    #pragma unroll
    for (int r = 0; r < LROWS; ++r){
      ps[r] += __shfl_xor(ps[r], o);
      pd[r] += __shfl_xor(pd[r], o);
    }
  }
  if (j == 0){
    #pragma unroll
    for (int r = 0; r < LROWS; ++r){ sred[w][r][0] = ps[r]; sred[w][r][1] = pd[r]; }
  }
  __syncthreads();
  if (t < LROWS * 2){
    int r = t >> 1, c = t & 1;
    float v = sred[0][r][c] + sred[1][r][c] + sred[2][r][c] + sred[3][r][c];
    int n = n0 + r;
    if (n < N){ if (c == 0) as2[n] = v; else ad2[n] = v; }
  }

  // ---- phase B: k-split over waves ----
  float acc2[LROWS];
  #pragma unroll
  for (int r = 0; r < LROWS; ++r) acc2[r] = 0.f;
  for (int k4 = 0; k4 < 32; ++k4){
    int k = w * 128 + k4 * 4;
    float w2v[4];
    #pragma unroll
    for (int kk = 0; kk < 4; ++kk) w2v[kk] = W2[(size_t)(k + kk) * 64 + j];
    #pragma unroll
    for (int r = 0; r < LROWS; ++r){
      float4 gv = *(const float4*)&gs[r][k];
      acc2[r] += gv.x * w2v[0] + gv.y * w2v[1] + gv.z * w2v[2] + gv.w * w2v[3];
    }
  }
  #pragma unroll
  for (int r = 0; r < LROWS; ++r) red2[w][r][j] = acc2[r];
  __syncthreads();
  #pragma unroll
  for (int i = 0; i < LROWS / 4; ++i){
    int r = i * 4 + w;
    float v = red2[0][r][j] + red2[1][r][j] + red2[2][r][j] + red2[3][r][j];
    int n = n0 + r;
    if (n < N) h2[(size_t)n * 64 + j] = v;
  }
}

// ---------------- mean pool + FC fused ----------------
__device__ __forceinline__ int lbound(const int* a, int n, int v){
  int lo = 0, hi = n;
  while (lo < hi){ int mid = (lo + hi) >> 1; if (a[mid] < v) lo = mid + 1; else hi = mid; }
  return lo;
}

__global__ __launch_bounds__(256) void k_poolfc(const float* __restrict__ g2, const int* __restrict__ batch,
                                                const float* __restrict__ fcW, const float* __restrict__ fcb,
                                                float* __restrict__ out, int N){
  int g = blockIdx.x;
  __shared__ int sb[2];
  if (threadIdx.x == 0){ sb[0] = lbound(batch, N, g); sb[1] = lbound(batch, N, g + 1); }
  __syncthreads();
  int r0 = sb[0], r1 = sb[1];
  int f = threadIdx.x & 63, ch = threadIdx.x >> 6;
  float s = 0.f;
  for (int r = r0 + ch; r < r1; r += 4) s += g2[(size_t)r * 64 + f];
  __shared__ float red[4][64];
  red[ch][f] = s;
  __syncthreads();
  if (ch == 0){
    float tot = red[0][f] + red[1][f] + red[2][f] + red[3][f];
    float c = fmaxf((float)(r1 - r0), 1.f);
    float p = tot / c;
    float o0 = p * fcW[f * 2 + 0];
    float o1 = p * fcW[f * 2 + 1];
    #pragma unroll
    for (int o = 32; o > 0; o >>= 1){ o0 += __shfl_xor(o0, o); o1 += __shfl_xor(o1, o); }
    if (f == 0){ out[g * 2 + 0] = o0 + fcb[0]; out[g * 2 + 1] = o1 + fcb[1]; }
  }
}

extern "C" void kernel_launch(void* const* d_in, const int* in_sizes, int n_in,
                              void* d_out, int out_size, void* d_ws, size_t ws_size,
                              hipStream_t stream){
  const float* x    = (const float*)d_in[0];
  const int* ei     = (const int*)d_in[1];
  const int* batch  = (const int*)d_in[2];
  const float* W1   = (const float*)d_in[3];
  const float* as1w = (const float*)d_in[4];
  const float* ad1w = (const float*)d_in[5];
  const float* b1   = (const float*)d_in[6];
  const float* W2   = (const float*)d_in[7];
  const float* as2w = (const float*)d_in[8];
  const float* ad2w = (const float*)d_in[9];
  const float* b2   = (const float*)d_in[10];
  const float* fcW  = (const float*)d_in[11];
  const float* fcb  = (const float*)d_in[12];
  float* out = (float*)d_out;

  const int N    = in_sizes[2];
  const int E    = in_sizes[1] / 2;
  const int NG   = out_size / 2;
  const int Etot = E + N;

  char* base = (char*)d_ws;
  size_t o = 0;
  auto take = [&](size_t bytes) -> char* {
    char* r = base + o;
    o = (o + bytes + 255) & ~(size_t)255;
    return r;
  };
  float* xa   = (float*)take((size_t)(N + 16) * 128 * 4);
  float* h2   = (float*)take((size_t)(N + 16) * 64 * 4);
  float* g2   = (float*)take((size_t)(N + 16) * 64 * 4);
  float* as1  = (float*)take((size_t)N * 4);
  float* ad1  = (float*)take((size_t)N * 4);
  float* as2  = (float*)take((size_t)N * 4);
  float* ad2  = (float*)take((size_t)N * 4);
  float* ws1  = (float*)take(128 * 4);
  float* wd1  = (float*)take(128 * 4);
  float* ws2  = (float*)take(512 * 4);
  float* wd2  = (float*)take(512 * 4);
  int*   deg  = (int*)take((size_t)N * 4);
  int*   offs = (int*)take((size_t)(N + 1) * 4);
  int*   cur  = (int*)take((size_t)N * 4);
  int*   csr  = (int*)take((size_t)Etot * 4);

  hipMemsetAsync(deg, 0, (size_t)N * 4, stream);
  hipMemsetAsync(cur, 0, (size_t)N * 4, stream);

  const int nDeg  = (Etot + 255) / 256;
  const int nWvec = 160;
  kA<<<nDeg + nWvec, 256, 0, stream>>>(ei, E, N, deg, W1, as1w, ad1w, W2, as2w, ad2w,
                                       ws1, wd1, ws2, wd2, nDeg);
  k_scan<<<1, 1024, 0, stream>>>(deg, offs, N);
  const int nScat = nDeg;
  kC<<<nScat + (N + 3) / 4, 256, 0, stream>>>(ei, E, N, offs, cur, csr, x, ws1, wd1, as1, ad1, nScat);

  k_aggw<128, false><<<(N + 3) / 4, 256, 0, stream>>>(offs, csr, as1, ad1, x, b1, xa, N);
  k_layer<<<(N + LROWS - 1) / LROWS, 256, 0, stream>>>(xa, W1, b1, W2, ws2, wd2, h2, as2, ad2, N);
  k_aggw<64, true><<<(N + 3) / 4, 256, 0, stream>>>(offs, csr, as2, ad2, h2, b2, g2, N);

  k_poolfc<<<NG, 256, 0, stream>>>(g2, batch, fcW, fcb, out, N);
}

// Round 7
// 106.587 us; speedup vs baseline: 2.7488x; 1.3066x over previous
//
#include <hip/hip_runtime.h>
#include <hip/hip_bf16.h>

#define NEG_SLOPE 0.2f

typedef __attribute__((ext_vector_type(8))) short bf16x8;
typedef __attribute__((ext_vector_type(4))) float f32x4;

__device__ __forceinline__ unsigned short f2bf(float f){
  __hip_bfloat16 h = __float2bfloat16(f);
  return *reinterpret_cast<unsigned short*>(&h);
}

// ---------------- kA: degree histogram + wvec + W1T/W2T bf16 transposes ----------------
__global__ __launch_bounds__(256) void kA(const int* __restrict__ ei, int E, int N,
                                          int* __restrict__ deg,
                                          const float* __restrict__ W1, const float* __restrict__ as1,
                                          const float* __restrict__ ad1,
                                          const float* __restrict__ W2, const float* __restrict__ as2,
                                          const float* __restrict__ ad2,
                                          float* __restrict__ ws1, float* __restrict__ wd1,
                                          float* __restrict__ ws2, float* __restrict__ wd2,
                                          unsigned short* __restrict__ W1T,
                                          unsigned short* __restrict__ W2T,
                                          int nDeg, int nWvec, int nW1T){
  int blk = blockIdx.x;
  int t = threadIdx.x;
  if (blk < nDeg){
    int i = blk * 256 + t;
    int Etot = E + N;
    if (i >= Etot) return;
    int d = (i < E) ? ei[E + i] : (i - E);
    atomicAdd(&deg[d], 1);
    return;
  }
  blk -= nDeg;
  if (blk < nWvec){
    int b = blk * 4 + (t >> 6);
    int l = t & 63;
    float s = 0.f, d = 0.f;
    if (b < 128){
      #pragma unroll
      for (int j = l; j < 512; j += 64){ float w = W1[b * 512 + j]; s += w * as1[j]; d += w * ad1[j]; }
    } else {
      int r = b - 128;
      float w = W2[r * 64 + l];
      s = w * as2[l]; d = w * ad2[l];
    }
    #pragma unroll
    for (int o = 32; o > 0; o >>= 1){ s += __shfl_xor(s, o); d += __shfl_xor(d, o); }
    if (l == 0){
      if (b < 128){ ws1[b] = s; wd1[b] = d; }
      else        { ws2[b - 128] = s; wd2[b - 128] = d; }
    }
    return;
  }
  blk -= nWvec;
  if (blk < nW1T){
    int idx = blk * 256 + t;          // over (k,c): coalesced read of W1[k][c]
    int k = idx >> 9, c = idx & 511;
    W1T[(size_t)c * 128 + k] = f2bf(W1[idx]);
    return;
  }
  blk -= nW1T;
  {
    int idx = blk * 256 + t;          // over (k,c) of W2[512][64]
    int k = idx >> 6, c = idx & 63;
    W2T[(size_t)c * 512 + k] = f2bf(W2[idx]);
  }
}

__global__ __launch_bounds__(1024) void k_scan(const int* __restrict__ deg, int* __restrict__ off, int n){
  __shared__ int lds[1024];
  int t = threadIdx.x;
  int per = (n + 1023) >> 10;
  int b = t * per, e = min(b + per, n);
  int sum = 0;
  for (int i = b; i < e; ++i) sum += deg[i];
  lds[t] = sum;
  __syncthreads();
  for (int d = 1; d < 1024; d <<= 1){
    int v = (t >= d) ? lds[t - d] : 0;
    __syncthreads();
    lds[t] += v;
    __syncthreads();
  }
  int run = (t == 0) ? 0 : lds[t - 1];
  for (int i = b; i < e; ++i){ off[i] = run; run += deg[i]; }
  if (t == 1023) off[n] = lds[1023];
}

// ---------------- kC: CSR scatter + layer-1 logit scalars ----------------
__global__ __launch_bounds__(256) void kC(const int* __restrict__ ei, int E, int N,
                                          const int* __restrict__ off, int* __restrict__ cur,
                                          int* __restrict__ csr,
                                          const float* __restrict__ x, const float* __restrict__ ws,
                                          const float* __restrict__ wd,
                                          float* __restrict__ as, float* __restrict__ ad,
                                          int nScat){
  int blk = blockIdx.x;
  if (blk < nScat){
    int i = blk * 256 + threadIdx.x;
    int Etot = E + N;
    if (i >= Etot) return;
    int s, d;
    if (i < E){ s = ei[i]; d = ei[E + i]; } else { s = i - E; d = i - E; }
    int p = off[d] + atomicAdd(&cur[d], 1);
    csr[p] = s;
    return;
  }
  int n = (blk - nScat) * 4 + (threadIdx.x >> 6);
  if (n >= N) return;
  int l = threadIdx.x & 63;
  float2 xv = ((const float2*)(x + (size_t)n * 128))[l];
  float2 sv = ((const float2*)ws)[l];
  float2 dv = ((const float2*)wd)[l];
  float s = xv.x * sv.x + xv.y * sv.y;
  float d = xv.x * dv.x + xv.y * dv.y;
  #pragma unroll
  for (int o = 32; o > 0; o >>= 1){ s += __shfl_xor(s, o); d += __shfl_xor(d, o); }
  if (l == 0){ as[n] = s; ad[n] = d; }
}

// ---------------- wave-per-node softmax aggregation ----------------
// F=128: gathers x (f32) -> xa (bf16).  F=64: gathers h2 (f32) -> g2 (f32, +bias+relu).
template<int F, bool EPI>
__global__ __launch_bounds__(256) void k_aggw(const int* __restrict__ off, const int* __restrict__ csr,
    const float* __restrict__ as, const float* __restrict__ ad, const float* __restrict__ h,
    const float* __restrict__ bias, void* __restrict__ out, int N){
  int n = blockIdx.x * 4 + (threadIdx.x >> 6);
  if (n >= N) return;
  int l = threadIdx.x & 63;
  int s0 = off[n];
  int deg = off[n + 1] - s0;
  float adv = ad[n];
  float m = -3.0e38f, ssum = 0.f;
  for (int i = l; i < deg; i += 64){
    int s = csr[s0 + i];
    float v = as[s] + adv;
    v = (v > 0.f) ? v : NEG_SLOPE * v;
    if (v > m){ ssum = ssum * __expf(m - v) + 1.f; m = v; }
    else ssum += __expf(v - m);
  }
  #pragma unroll
  for (int o = 32; o > 0; o >>= 1){
    float m2 = __shfl_xor(m, o);
    float s2 = __shfl_xor(ssum, o);
    float mm = fmaxf(m, m2);
    float ns = 0.f;
    if (ssum > 0.f) ns += ssum * __expf(m - mm);
    if (s2  > 0.f) ns += s2  * __expf(m2 - mm);
    m = mm; ssum = ns;
  }
  float inv = 1.0f / ssum;

  constexpr int EPG = (F == 128) ? 2 : 4;
  constexpr int FL  = (F == 128) ? 32 : 16;
  int p = l / FL;
  int f = l % FL;
  float4 acc = make_float4(0.f, 0.f, 0.f, 0.f);
  for (int base = 0; base < deg; base += 64){
    int idx = base + l;
    float al = 0.f; int sr = 0;
    if (idx < deg){
      sr = csr[s0 + idx];
      float v = as[sr] + adv;
      v = (v > 0.f) ? v : NEG_SLOPE * v;
      al = __expf(v - m) * inv;
    }
    int cnt = min(64, deg - base);
    int steps = (cnt + EPG - 1) / EPG;
    #pragma unroll 4
    for (int i = 0; i < steps; ++i){
      int e = i * EPG + p;
      float a = __shfl(al, e);
      int s  = __shfl(sr, e);
      float4 hv = ((const float4*)(h + (size_t)s * F))[f];
      acc.x += a * hv.x; acc.y += a * hv.y; acc.z += a * hv.z; acc.w += a * hv.w;
    }
  }
  if (F == 64){
    acc.x += __shfl_xor(acc.x, 16); acc.y += __shfl_xor(acc.y, 16);
    acc.z += __shfl_xor(acc.z, 16); acc.w += __shfl_xor(acc.w, 16);
  }
  acc.x += __shfl_xor(acc.x, 32); acc.y += __shfl_xor(acc.y, 32);
  acc.z += __shfl_xor(acc.z, 32); acc.w += __shfl_xor(acc.w, 32);
  if (l < FL){
    if (F == 128){
      unsigned short* ob = (unsigned short*)out;
      unsigned int p0 = (unsigned int)f2bf(acc.x) | ((unsigned int)f2bf(acc.y) << 16);
      unsigned int p1 = (unsigned int)f2bf(acc.z) | ((unsigned int)f2bf(acc.w) << 16);
      *(uint2*)(ob + (size_t)n * 128 + f * 4) = make_uint2(p0, p1);
    } else {
      float* ob = (float*)out;
      if (EPI){
        float4 bv = ((const float4*)bias)[f];
        acc.x = fmaxf(acc.x + bv.x, 0.f); acc.y = fmaxf(acc.y + bv.y, 0.f);
        acc.z = fmaxf(acc.z + bv.z, 0.f); acc.w = fmaxf(acc.w + bv.w, 0.f);
      }
      ((float4*)(ob + (size_t)n * F))[f] = acc;
    }
  }
}

// ---------------- fused layer kernel v4: MFMA bf16 ----------------
// 16 rows/block, 256 thr. Phase A: wave w -> cols [w*128,+128), mfma 16x16x32, W1T read once/block.
// Phase B: wave w -> out-cols [w*16,+16), full K=512 from gs, W2T read once/block.
#define LROWS 16
__global__ __launch_bounds__(256) void k_layer(
    const unsigned short* __restrict__ xab, const unsigned short* __restrict__ W1T,
    const float* __restrict__ b1,
    const unsigned short* __restrict__ W2T, const float* __restrict__ ws2,
    const float* __restrict__ wd2,
    float* __restrict__ h2, float* __restrict__ as2, float* __restrict__ ad2, int N){
  __shared__ __align__(16) unsigned short xs[16 * 136];   // pad 8: 2-way bank alias only
  __shared__ __align__(16) unsigned short gs[16 * 520];   // pad 8
  __shared__ float sred[4][16][2];
  int t = threadIdx.x;
  int w = t >> 6, l = t & 63;
  int lg = l >> 4, ln = l & 15;
  int n0 = blockIdx.x * LROWS;

  {
    int row = t >> 4, seg = t & 15;
    int n = n0 + row; if (n >= N) n = N - 1;
    *(int4*)&xs[row * 136 + seg * 8] = *(const int4*)&xab[(size_t)n * 128 + seg * 8];
  }
  __syncthreads();

  // ---- phase A ----
  int c0 = w * 128;
  bf16x8 af[4];
  #pragma unroll
  for (int kt = 0; kt < 4; ++kt)
    af[kt] = *reinterpret_cast<const bf16x8*>(&xs[ln * 136 + kt * 32 + lg * 8]);

  f32x4 acc[8];
  #pragma unroll
  for (int nt = 0; nt < 8; ++nt) acc[nt] = (f32x4){0.f, 0.f, 0.f, 0.f};
  #pragma unroll
  for (int nt = 0; nt < 8; ++nt){
    const unsigned short* wp = W1T + (size_t)(c0 + nt * 16 + ln) * 128 + lg * 8;
    #pragma unroll
    for (int kt = 0; kt < 4; ++kt){
      bf16x8 bfr = *reinterpret_cast<const bf16x8*>(wp + kt * 32);
      acc[nt] = __builtin_amdgcn_mfma_f32_16x16x32_bf16(af[kt], bfr, acc[nt], 0, 0, 0);
    }
  }

  // epilogue A: bias+relu, write gs (bf16), partial ws2/wd2 dots
  float ps4[4] = {0, 0, 0, 0}, pd4[4] = {0, 0, 0, 0};
  #pragma unroll
  for (int nt = 0; nt < 8; ++nt){
    int col = c0 + nt * 16 + ln;
    float bb = b1[col], wsv = ws2[col], wdv = wd2[col];
    #pragma unroll
    for (int r = 0; r < 4; ++r){
      float g = fmaxf(acc[nt][r] + bb, 0.f);
      gs[(lg * 4 + r) * 520 + col] = f2bf(g);
      ps4[r] += g * wsv;
      pd4[r] += g * wdv;
    }
  }
  #pragma unroll
  for (int o = 1; o < 16; o <<= 1){
    #pragma unroll
    for (int r = 0; r < 4; ++r){ ps4[r] += __shfl_xor(ps4[r], o); pd4[r] += __shfl_xor(pd4[r], o); }
  }
  if (ln == 0){
    #pragma unroll
    for (int r = 0; r < 4; ++r){ sred[w][lg * 4 + r][0] = ps4[r]; sred[w][lg * 4 + r][1] = pd4[r]; }
  }
  __syncthreads();
  if (t < 32){
    int r = t >> 1, c = t & 1;
    float v = sred[0][r][c] + sred[1][r][c] + sred[2][r][c] + sred[3][r][c];
    int n = n0 + r;
    if (n < N){ if (c == 0) as2[n] = v; else ad2[n] = v; }
  }

  // ---- phase B: wave w -> output cols [w*16, +16), K = 512 ----
  f32x4 a0 = (f32x4){0.f, 0.f, 0.f, 0.f}, a1 = (f32x4){0.f, 0.f, 0.f, 0.f};
  const unsigned short* wp2 = W2T + (size_t)(w * 16 + ln) * 512 + lg * 8;
  #pragma unroll
  for (int kt = 0; kt < 16; kt += 2){
    bf16x8 afa = *reinterpret_cast<const bf16x8*>(&gs[ln * 520 + kt * 32 + lg * 8]);
    bf16x8 bfa = *reinterpret_cast<const bf16x8*>(wp2 + kt * 32);
    a0 = __builtin_amdgcn_mfma_f32_16x16x32_bf16(afa, bfa, a0, 0, 0, 0);
    bf16x8 afb = *reinterpret_cast<const bf16x8*>(&gs[ln * 520 + (kt + 1) * 32 + lg * 8]);
    bf16x8 bfb = *reinterpret_cast<const bf16x8*>(wp2 + (kt + 1) * 32);
    a1 = __builtin_amdgcn_mfma_f32_16x16x32_bf16(afb, bfb, a1, 0, 0, 0);
  }
  #pragma unroll
  for (int r = 0; r < 4; ++r){
    int n = n0 + lg * 4 + r;
    if (n < N) h2[(size_t)n * 64 + w * 16 + ln] = a0[r] + a1[r];
  }
}

// ---------------- mean pool + FC fused ----------------
__device__ __forceinline__ int lbound(const int* a, int n, int v){
  int lo = 0, hi = n;
  while (lo < hi){ int mid = (lo + hi) >> 1; if (a[mid] < v) lo = mid + 1; else hi = mid; }
  return lo;
}

__global__ __launch_bounds__(256) void k_poolfc(const float* __restrict__ g2, const int* __restrict__ batch,
                                                const float* __restrict__ fcW, const float* __restrict__ fcb,
                                                float* __restrict__ out, int N){
  int g = blockIdx.x;
  __shared__ int sb[2];
  if (threadIdx.x == 0){ sb[0] = lbound(batch, N, g); sb[1] = lbound(batch, N, g + 1); }
  __syncthreads();
  int r0 = sb[0], r1 = sb[1];
  int f = threadIdx.x & 63, ch = threadIdx.x >> 6;
  float s = 0.f;
  for (int r = r0 + ch; r < r1; r += 4) s += g2[(size_t)r * 64 + f];
  __shared__ float red[4][64];
  red[ch][f] = s;
  __syncthreads();
  if (ch == 0){
    float tot = red[0][f] + red[1][f] + red[2][f] + red[3][f];
    float c = fmaxf((float)(r1 - r0), 1.f);
    float p = tot / c;
    float o0 = p * fcW[f * 2 + 0];
    float o1 = p * fcW[f * 2 + 1];
    #pragma unroll
    for (int o = 32; o > 0; o >>= 1){ o0 += __shfl_xor(o0, o); o1 += __shfl_xor(o1, o); }
    if (f == 0){ out[g * 2 + 0] = o0 + fcb[0]; out[g * 2 + 1] = o1 + fcb[1]; }
  }
}

extern "C" void kernel_launch(void* const* d_in, const int* in_sizes, int n_in,
                              void* d_out, int out_size, void* d_ws, size_t ws_size,
                              hipStream_t stream){
  const float* x    = (const float*)d_in[0];
  const int* ei     = (const int*)d_in[1];
  const int* batch  = (const int*)d_in[2];
  const float* W1   = (const float*)d_in[3];
  const float* as1w = (const float*)d_in[4];
  const float* ad1w = (const float*)d_in[5];
  const float* b1   = (const float*)d_in[6];
  const float* W2   = (const float*)d_in[7];
  const float* as2w = (const float*)d_in[8];
  const float* ad2w = (const float*)d_in[9];
  const float* b2   = (const float*)d_in[10];
  const float* fcW  = (const float*)d_in[11];
  const float* fcb  = (const float*)d_in[12];
  float* out = (float*)d_out;

  const int N    = in_sizes[2];
  const int E    = in_sizes[1] / 2;
  const int NG   = out_size / 2;
  const int Etot = E + N;

  char* base = (char*)d_ws;
  size_t o = 0;
  auto take = [&](size_t bytes) -> char* {
    char* r = base + o;
    o = (o + bytes + 255) & ~(size_t)255;
    return r;
  };
  unsigned short* xa  = (unsigned short*)take((size_t)(N + 16) * 128 * 2);
  float* h2   = (float*)take((size_t)(N + 16) * 64 * 4);
  float* g2   = (float*)take((size_t)(N + 16) * 64 * 4);
  float* as1  = (float*)take((size_t)N * 4);
  float* ad1  = (float*)take((size_t)N * 4);
  float* as2  = (float*)take((size_t)N * 4);
  float* ad2  = (float*)take((size_t)N * 4);
  float* ws1  = (float*)take(128 * 4);
  float* wd1  = (float*)take(128 * 4);
  float* ws2  = (float*)take(512 * 4);
  float* wd2  = (float*)take(512 * 4);
  unsigned short* W1T = (unsigned short*)take((size_t)128 * 512 * 2);
  unsigned short* W2T = (unsigned short*)take((size_t)512 * 64 * 2);
  int*   deg  = (int*)take((size_t)N * 4);
  int*   offs = (int*)take((size_t)(N + 1) * 4);
  int*   cur  = (int*)take((size_t)N * 4);
  int*   csr  = (int*)take((size_t)Etot * 4);

  hipMemsetAsync(deg, 0, (size_t)N * 4, stream);
  hipMemsetAsync(cur, 0, (size_t)N * 4, stream);

  const int nDeg  = (Etot + 255) / 256;
  const int nWvec = 160;
  const int nW1T  = (128 * 512) / 256;   // 256
  const int nW2T  = (512 * 64) / 256;    // 128
  kA<<<nDeg + nWvec + nW1T + nW2T, 256, 0, stream>>>(ei, E, N, deg, W1, as1w, ad1w, W2, as2w, ad2w,
                                                     ws1, wd1, ws2, wd2, W1T, W2T, nDeg, nWvec, nW1T);
  k_scan<<<1, 1024, 0, stream>>>(deg, offs, N);
  const int nScat = nDeg;
  kC<<<nScat + (N + 3) / 4, 256, 0, stream>>>(ei, E, N, offs, cur, csr, x, ws1, wd1, as1, ad1, nScat);

  k_aggw<128, false><<<(N + 3) / 4, 256, 0, stream>>>(offs, csr, as1, ad1, x, b1, (void*)xa, N);
  k_layer<<<(N + LROWS - 1) / LROWS, 256, 0, stream>>>(xa, W1T, b1, W2T, ws2, wd2, h2, as2, ad2, N);
  k_aggw<64, true><<<(N + 3) / 4, 256, 0, stream>>>(offs, csr, as2, ad2, h2, b2, (void*)g2, N);

  k_poolfc<<<NG, 256, 0, stream>>>(g2, batch, fcW, fcb, out, N);
}